// Round 1
// baseline (154.467 us; speedup 1.0000x reference)
//
#include <hip/hip_runtime.h>

// Problem constants (from reference)
#define NP   8192   // NUM_P
#define MS   8192   // M
#define DXC  16
#define DUC  8

// Workspace layout in floats:
//   mu    : [8192 * 16]
//   a1    : [8192]        a1[j] = lw[j] - 0.5*||mu_j||^2
//   a2    : [8192]        a2[i] = w[i] - L1[i]
//   part1 : [32 * 8192]   partial exp-sums over j-chunks (indexed by i)
//   part2 : [32 * 8192]   partial exp-sums over i-chunks (indexed by j)
#define WS_MU 0
#define WS_A1 131072
#define WS_A2 139264
#define WS_P1 147456
#define WS_P2 409600
// total = 671744 floats = 2.625 MB

__device__ __forceinline__ float dot4(float4 a, float4 b) {
  return a.x * b.x + a.y * b.y + a.z * b.z + a.w * b.w;
}

// mu = x @ A^T + u @ B^T ; a1[j] = lw[j] - 0.5*||mu_j||^2
__global__ __launch_bounds__(256) void k_prep(
    const float* __restrict__ particles, const float* __restrict__ lw,
    const float* __restrict__ A, const float* __restrict__ B,
    float* __restrict__ mu, float* __restrict__ a1) {
  int j = blockIdx.x * 256 + threadIdx.x;
  const float* p = particles + (size_t)j * (DXC + DUC);
  float x[DXC + DUC];
#pragma unroll
  for (int q = 0; q < 6; ++q) {
    float4 v = ((const float4*)p)[q];
    x[q * 4 + 0] = v.x; x[q * 4 + 1] = v.y;
    x[q * 4 + 2] = v.z; x[q * 4 + 3] = v.w;
  }
  float mrow[DXC];
  float m2 = 0.f;
#pragma unroll
  for (int k = 0; k < DXC; ++k) {
    float s = 0.f;
#pragma unroll
    for (int l = 0; l < DXC; ++l) s += x[l] * A[k * DXC + l];      // A uniform -> scalar loads
#pragma unroll
    for (int l = 0; l < DUC; ++l) s += x[DXC + l] * B[k * DUC + l];
    mrow[k] = s;
    m2 += s * s;
  }
  float4* dst = (float4*)(mu + (size_t)j * DXC);
#pragma unroll
  for (int q = 0; q < 4; ++q) {
    dst[q] = make_float4(mrow[q * 4 + 0], mrow[q * 4 + 1],
                         mrow[q * 4 + 2], mrow[q * 4 + 3]);
  }
  a1[j] = lw[j] - 0.5f * m2;
}

// Generic fused pass:
//   part[c][r] = sum over tile rows tt in chunk c of exp(addv[tt] + dot(statv_r, tilev_tt))
// Pass 1: statv = samples_p (rows i), tilev = mu (rows j), addv = a1  -> partials of exp-sum for L1[i]
// Pass 2: statv = mu (rows j), tilev = samples_p (rows i), addv = a2  -> partials of exp-sum for L2[j]
// Grid: (16, 32); block 256. Each thread owns 2 stationary rows (r0, r0+256),
// each blockIdx.y owns a 256-row tile chunk staged in LDS (broadcast reads).
__global__ __launch_bounds__(256) void k_pass(
    const float* __restrict__ statv,
    const float* __restrict__ tilev,
    const float* __restrict__ addv,
    float* __restrict__ part) {
  __shared__ float tl[256 * 16];
  __shared__ float ad[256];
  int t = threadIdx.x;
  int c = blockIdx.y;
  int r0 = blockIdx.x * 512 + t;

  {
    const float4* src = (const float4*)(tilev + (size_t)c * 256 * 16);
    float4* dst4 = (float4*)tl;
#pragma unroll
    for (int q = 0; q < 4; ++q) dst4[t + 256 * q] = src[t + 256 * q];
    ad[t] = addv[c * 256 + t];
  }
  __syncthreads();

  float4 s0[4], s1[4];
  {
    const float4* r0p = (const float4*)(statv + (size_t)r0 * 16);
    const float4* r1p = (const float4*)(statv + (size_t)(r0 + 256) * 16);
#pragma unroll
    for (int q = 0; q < 4; ++q) { s0[q] = r0p[q]; s1[q] = r1p[q]; }
  }

  float acc0 = 0.f, acc1 = 0.f;
#pragma unroll 4
  for (int jj = 0; jj < 256; ++jj) {
    const float4* mr = (const float4*)(tl + jj * 16);
    float4 m0 = mr[0], m1 = mr[1], m2 = mr[2], m3 = mr[3];
    float av = ad[jj];
    float d0 = dot4(s0[0], m0) + dot4(s0[1], m1) + dot4(s0[2], m2) + dot4(s0[3], m3);
    float d1 = dot4(s1[0], m0) + dot4(s1[1], m1) + dot4(s1[2], m2) + dot4(s1[3], m3);
    acc0 += __expf(av + d0);
    acc1 += __expf(av + d1);
  }
  part[(size_t)c * 8192 + r0] = acc0;
  part[(size_t)c * 8192 + r0 + 256] = acc1;
}

// a2[i] = w[i] - log(sum_c part1[c][i])
__global__ __launch_bounds__(256) void k_red_a2(
    const float* __restrict__ part1, const float* __restrict__ w,
    float* __restrict__ a2) {
  int i = blockIdx.x * 256 + threadIdx.x;
  float s = 0.f;
#pragma unroll
  for (int c = 0; c < 32; ++c) s += part1[(size_t)c * 8192 + i];
  a2[i] = w[i] - __logf(s);
}

// out[j] = a1[j] + log(sum_c part2[c][j])
__global__ __launch_bounds__(256) void k_out(
    const float* __restrict__ part2, const float* __restrict__ a1,
    float* __restrict__ out) {
  int j = blockIdx.x * 256 + threadIdx.x;
  float s = 0.f;
#pragma unroll
  for (int c = 0; c < 32; ++c) s += part2[(size_t)c * 8192 + j];
  out[j] = a1[j] + __logf(s);
}

extern "C" void kernel_launch(void* const* d_in, const int* in_sizes, int n_in,
                              void* d_out, int out_size, void* d_ws, size_t ws_size,
                              hipStream_t stream) {
  const float* particles = (const float*)d_in[0];  // 8192 x 24
  const float* lw        = (const float*)d_in[1];  // 8192
  const float* sp        = (const float*)d_in[2];  // 8192 x 16
  const float* w         = (const float*)d_in[3];  // 8192
  const float* A         = (const float*)d_in[4];  // 16 x 16
  const float* B         = (const float*)d_in[5];  // 16 x 8
  // d_in[6] = samples_idx : unused by the reference computation

  float* ws = (float*)d_ws;
  float* mu = ws + WS_MU;
  float* a1 = ws + WS_A1;
  float* a2 = ws + WS_A2;
  float* p1 = ws + WS_P1;
  float* p2 = ws + WS_P2;
  float* out = (float*)d_out;

  k_prep<<<dim3(32), dim3(256), 0, stream>>>(particles, lw, A, B, mu, a1);
  k_pass<<<dim3(16, 32), dim3(256), 0, stream>>>(sp, mu, a1, p1);
  k_red_a2<<<dim3(32), dim3(256), 0, stream>>>(p1, w, a2);
  k_pass<<<dim3(16, 32), dim3(256), 0, stream>>>(mu, sp, a2, p2);
  k_out<<<dim3(32), dim3(256), 0, stream>>>(p2, a1, out);
}

// Round 2
// 88.507 us; speedup vs baseline: 1.7453x; 1.7453x over previous
//
#include <hip/hip_runtime.h>

#define LOG2E 1.44269504088896340736f
#define LN2   0.69314718055994530942f

typedef __attribute__((ext_vector_type(8))) short bf16x8;
typedef __attribute__((ext_vector_type(4))) float f32x4;

// ws float offsets
//   muP : 8192 rows x 16 u32  (packed 32 bf16 per row: [mu_hi(16) | mu_lo(16)])
//   spT : 8192 rows x 16 u32  (packed 32 bf16 per row: [sp'_hi    | sp'_lo  ], sp' = log2e * sp)
//   av1 : 8192 f32            (log2e * (lw - 0.5*||mu||^2))
//   av2 : 8192 f32            (log2e * w - log2(S1))
//   part: 32 x 8192 f32       (per-chunk partial exp2-sums; reused by both passes)
#define WS_MUP  0
#define WS_SPT  131072
#define WS_AV1  262144
#define WS_AV2  270336
#define WS_PART 278528
// total = 540672 floats = 2.11 MB

__device__ __forceinline__ unsigned short bf16_rne(float x) {
  unsigned int u = __float_as_uint(x);
  u = u + 0x7FFFu + ((u >> 16) & 1u);
  return (unsigned short)(u >> 16);
}
__device__ __forceinline__ float bf16f(unsigned short h) {
  return __uint_as_float(((unsigned int)h) << 16);
}
__device__ __forceinline__ float fast_exp2(float x) {
#if __has_builtin(__builtin_amdgcn_exp2f)
  return __builtin_amdgcn_exp2f(x);
#else
  return exp2f(x);
#endif
}
__device__ __forceinline__ float fast_log2(float x) {
#if __has_builtin(__builtin_amdgcn_logf)
  return __builtin_amdgcn_logf(x);
#else
  return log2f(x);
#endif
}

__device__ __forceinline__ void pack_row(const float* v, unsigned int* buf) {
  // buf[0..7] = hi parts (16 bf16), buf[8..15] = lo parts
#pragma unroll
  for (int k = 0; k < 16; k += 2) {
    unsigned short h0 = bf16_rne(v[k]);
    unsigned short h1 = bf16_rne(v[k + 1]);
    float l0 = v[k] - bf16f(h0);
    float l1 = v[k + 1] - bf16f(h1);
    buf[k >> 1] = (unsigned int)h0 | ((unsigned int)h1 << 16);
    buf[8 + (k >> 1)] = (unsigned int)bf16_rne(l0) | ((unsigned int)bf16_rne(l1) << 16);
  }
}

// Per row j: mu_j = A x_j + B u_j ; av1[j] = log2e*(lw_j - 0.5||mu_j||^2);
// pack muP[j] = split(mu_j), spT[j] = split(log2e * sp_j).
__global__ __launch_bounds__(256) void k_prep(
    const float* __restrict__ particles, const float* __restrict__ lw,
    const float* __restrict__ sp,
    const float* __restrict__ A, const float* __restrict__ B,
    unsigned int* __restrict__ muP, unsigned int* __restrict__ spT,
    float* __restrict__ av1) {
  int j = blockIdx.x * 256 + threadIdx.x;
  float x[24];
  {
    const float4* p4 = (const float4*)(particles + (size_t)j * 24);
#pragma unroll
    for (int q = 0; q < 6; ++q) {
      float4 v = p4[q];
      x[q * 4 + 0] = v.x; x[q * 4 + 1] = v.y; x[q * 4 + 2] = v.z; x[q * 4 + 3] = v.w;
    }
  }
  float mrow[16];
  float m2 = 0.f;
#pragma unroll
  for (int k = 0; k < 16; ++k) {
    float s = 0.f;
#pragma unroll
    for (int l = 0; l < 16; ++l) s += x[l] * A[k * 16 + l];   // uniform -> scalar loads
#pragma unroll
    for (int l = 0; l < 8; ++l) s += x[16 + l] * B[k * 8 + l];
    mrow[k] = s;
    m2 += s * s;
  }
  av1[j] = LOG2E * (lw[j] - 0.5f * m2);

  unsigned int buf[16];
  pack_row(mrow, buf);
  {
    uint4* dst = (uint4*)(muP + (size_t)j * 16);
#pragma unroll
    for (int q = 0; q < 4; ++q)
      dst[q] = make_uint4(buf[q * 4], buf[q * 4 + 1], buf[q * 4 + 2], buf[q * 4 + 3]);
  }
  float srow[16];
  {
    const float4* s4 = (const float4*)(sp + (size_t)j * 16);
#pragma unroll
    for (int q = 0; q < 4; ++q) {
      float4 v = s4[q];
      srow[q * 4 + 0] = LOG2E * v.x; srow[q * 4 + 1] = LOG2E * v.y;
      srow[q * 4 + 2] = LOG2E * v.z; srow[q * 4 + 3] = LOG2E * v.w;
    }
  }
  pack_row(srow, buf);
  {
    uint4* dst = (uint4*)(spT + (size_t)j * 16);
#pragma unroll
    for (int q = 0; q < 4; ++q)
      dst[q] = make_uint4(buf[q * 4], buf[q * 4 + 1], buf[q * 4 + 2], buf[q * 4 + 3]);
  }
}

// part[chunk][r] = sum over 256 tile rows t in chunk of 2^( avv[t] + stat_r . tile_t )
// Tile rows are the MFMA A operand (M), stationary rows the B operand (N).
// Each wave owns 64 stationary rows (4 strips of 16, B-frags in registers) and
// walks 16 t-tiles of 16. av is folded in as the MFMA C operand.
__global__ __launch_bounds__(256, 4) void k_pass(
    const unsigned int* __restrict__ tilev,
    const unsigned int* __restrict__ statv,
    const float* __restrict__ avv,
    float* __restrict__ part) {
  __shared__ __align__(16) float tl[256 * 20];  // 64B data + 16B pad per row
  __shared__ __align__(16) float av_lds[256];
  const int t = threadIdx.x;
  const int chunk = blockIdx.y;
  {
    const float4* src = (const float4*)(tilev + (size_t)chunk * 256 * 16);
#pragma unroll
    for (int q = 0; q < 4; ++q) {
      int f = t + 256 * q;
      int row = f >> 2, prt = f & 3;
      *(float4*)(tl + row * 20 + prt * 4) = src[f];
    }
    av_lds[t] = avv[chunk * 256 + t];
  }
  __syncthreads();

  const int wave = t >> 6;
  const int l = t & 63;
  const int lr = l & 15;   // A-row / D-col / B-col selector
  const int g = l >> 4;    // k-group
  const int r0 = (blockIdx.x * 4 + wave) * 64;

  bf16x8 b1[4], b2[4];
#pragma unroll
  for (int s = 0; s < 4; ++s) {
    const unsigned int* rowp = statv + (size_t)(r0 + s * 16 + lr) * 16;
    b1[s] = *(const bf16x8*)(rowp + (g & 1) * 4);      // [bh | bh]
    b2[s] = *(const bf16x8*)(rowp + 8 + (g & 1) * 4);  // [bl | bl]
  }

  float acc[4] = {0.f, 0.f, 0.f, 0.f};
#pragma unroll
  for (int tile = 0; tile < 16; ++tile) {
    const bf16x8 af = *(const bf16x8*)(tl + (tile * 16 + lr) * 20 + g * 4);
    const f32x4 avf = *(const f32x4*)(av_lds + tile * 16 + g * 4);
#pragma unroll
    for (int s = 0; s < 4; ++s) {
      f32x4 d = __builtin_amdgcn_mfma_f32_16x16x32_bf16(af, b1[s], avf, 0, 0, 0);
      d = __builtin_amdgcn_mfma_f32_16x16x32_bf16(af, b2[s], d, 0, 0, 0);
      acc[s] += (fast_exp2(d[0]) + fast_exp2(d[1])) + (fast_exp2(d[2]) + fast_exp2(d[3]));
    }
  }
#pragma unroll
  for (int s = 0; s < 4; ++s) {
    float v = acc[s];
    v += __shfl_xor(v, 16);
    v += __shfl_xor(v, 32);
    if (l < 16) part[(size_t)chunk * 8192 + r0 + s * 16 + l] = v;
  }
}

// av2[i] = log2e * w[i] - log2( sum_c part[c][i] )
__global__ __launch_bounds__(256) void k_red_a2(
    const float* __restrict__ part, const float* __restrict__ w,
    float* __restrict__ av2) {
  int i = blockIdx.x * 256 + threadIdx.x;
  float s = 0.f;
#pragma unroll
  for (int c = 0; c < 32; ++c) s += part[(size_t)c * 8192 + i];
  av2[i] = LOG2E * w[i] - fast_log2(s);
}

// out[j] = ln2 * ( av1[j] + log2( sum_c part[c][j] ) )
__global__ __launch_bounds__(256) void k_out(
    const float* __restrict__ part, const float* __restrict__ av1,
    float* __restrict__ out) {
  int j = blockIdx.x * 256 + threadIdx.x;
  float s = 0.f;
#pragma unroll
  for (int c = 0; c < 32; ++c) s += part[(size_t)c * 8192 + j];
  out[j] = LN2 * (av1[j] + fast_log2(s));
}

extern "C" void kernel_launch(void* const* d_in, const int* in_sizes, int n_in,
                              void* d_out, int out_size, void* d_ws, size_t ws_size,
                              hipStream_t stream) {
  const float* particles = (const float*)d_in[0];
  const float* lw        = (const float*)d_in[1];
  const float* sp        = (const float*)d_in[2];
  const float* w         = (const float*)d_in[3];
  const float* A         = (const float*)d_in[4];
  const float* B         = (const float*)d_in[5];

  float* ws = (float*)d_ws;
  unsigned int* muP = (unsigned int*)(ws + WS_MUP);
  unsigned int* spT = (unsigned int*)(ws + WS_SPT);
  float* av1  = ws + WS_AV1;
  float* av2  = ws + WS_AV2;
  float* part = ws + WS_PART;
  float* out  = (float*)d_out;

  k_prep<<<dim3(32), dim3(256), 0, stream>>>(particles, lw, sp, A, B, muP, spT, av1);
  // pass 1: tile = mu (j), stationary = sp' (i)  -> S1 per i
  k_pass<<<dim3(32, 32), dim3(256), 0, stream>>>(muP, spT, av1, part);
  k_red_a2<<<dim3(32), dim3(256), 0, stream>>>(part, w, av2);
  // pass 2: tile = sp' (i), stationary = mu (j)  -> S2 per j
  k_pass<<<dim3(32, 32), dim3(256), 0, stream>>>(spT, muP, av2, part);
  k_out<<<dim3(32), dim3(256), 0, stream>>>(part, av1, out);
}

// Round 3
// 87.702 us; speedup vs baseline: 1.7613x; 1.0092x over previous
//
#include <hip/hip_runtime.h>

#define LOG2E 1.44269504088896340736f
#define LN2   0.69314718055994530942f

typedef __attribute__((ext_vector_type(8))) short bf16x8;
typedef __attribute__((ext_vector_type(4))) float f32x4;

// ws float offsets
//   muP : 8192 rows x 16 u32  (packed 32 bf16 per row: [mu_hi(16) | mu_lo(16)])
//   spT : 8192 rows x 16 u32  (packed 32 bf16 per row: [sp'_hi    | sp'_lo  ], sp' = log2e * sp)
//   av1 : 8192 f32            (log2e * (lw - 0.5*||mu||^2))
//   av2 : 8192 f32            (log2e * w - log2(S1))
//   part: 32 x 8192 f32       (per-chunk partial exp2-sums; reused by both passes)
#define WS_MUP  0
#define WS_SPT  131072
#define WS_AV1  262144
#define WS_AV2  270336
#define WS_PART 278528

__device__ __forceinline__ unsigned short bf16_rne(float x) {
  unsigned int u = __float_as_uint(x);
  u = u + 0x7FFFu + ((u >> 16) & 1u);
  return (unsigned short)(u >> 16);
}
__device__ __forceinline__ float bf16f(unsigned short h) {
  return __uint_as_float(((unsigned int)h) << 16);
}
__device__ __forceinline__ float fast_exp2(float x) {
#if __has_builtin(__builtin_amdgcn_exp2f)
  return __builtin_amdgcn_exp2f(x);
#else
  return exp2f(x);
#endif
}
__device__ __forceinline__ float fast_log2(float x) {
#if __has_builtin(__builtin_amdgcn_logf)
  return __builtin_amdgcn_logf(x);
#else
  return log2f(x);
#endif
}

__device__ __forceinline__ void pack_row(const float* v, unsigned int* buf) {
  // buf[0..7] = hi parts (16 bf16), buf[8..15] = lo parts
#pragma unroll
  for (int k = 0; k < 16; k += 2) {
    unsigned short h0 = bf16_rne(v[k]);
    unsigned short h1 = bf16_rne(v[k + 1]);
    float l0 = v[k] - bf16f(h0);
    float l1 = v[k + 1] - bf16f(h1);
    buf[k >> 1] = (unsigned int)h0 | ((unsigned int)h1 << 16);
    buf[8 + (k >> 1)] = (unsigned int)bf16_rne(l0) | ((unsigned int)bf16_rne(l1) << 16);
  }
}

__global__ __launch_bounds__(256) void k_prep(
    const float* __restrict__ particles, const float* __restrict__ lw,
    const float* __restrict__ sp,
    const float* __restrict__ A, const float* __restrict__ B,
    unsigned int* __restrict__ muP, unsigned int* __restrict__ spT,
    float* __restrict__ av1) {
  int j = blockIdx.x * 256 + threadIdx.x;
  float x[24];
  {
    const float4* p4 = (const float4*)(particles + (size_t)j * 24);
#pragma unroll
    for (int q = 0; q < 6; ++q) {
      float4 v = p4[q];
      x[q * 4 + 0] = v.x; x[q * 4 + 1] = v.y; x[q * 4 + 2] = v.z; x[q * 4 + 3] = v.w;
    }
  }
  float mrow[16];
  float m2 = 0.f;
#pragma unroll
  for (int k = 0; k < 16; ++k) {
    float s = 0.f;
#pragma unroll
    for (int l = 0; l < 16; ++l) s += x[l] * A[k * 16 + l];   // uniform -> scalar loads
#pragma unroll
    for (int l = 0; l < 8; ++l) s += x[16 + l] * B[k * 8 + l];
    mrow[k] = s;
    m2 += s * s;
  }
  av1[j] = LOG2E * (lw[j] - 0.5f * m2);

  unsigned int buf[16];
  pack_row(mrow, buf);
  {
    uint4* dst = (uint4*)(muP + (size_t)j * 16);
#pragma unroll
    for (int q = 0; q < 4; ++q)
      dst[q] = make_uint4(buf[q * 4], buf[q * 4 + 1], buf[q * 4 + 2], buf[q * 4 + 3]);
  }
  float srow[16];
  {
    const float4* s4 = (const float4*)(sp + (size_t)j * 16);
#pragma unroll
    for (int q = 0; q < 4; ++q) {
      float4 v = s4[q];
      srow[q * 4 + 0] = LOG2E * v.x; srow[q * 4 + 1] = LOG2E * v.y;
      srow[q * 4 + 2] = LOG2E * v.z; srow[q * 4 + 3] = LOG2E * v.w;
    }
  }
  pack_row(srow, buf);
  {
    uint4* dst = (uint4*)(spT + (size_t)j * 16);
#pragma unroll
    for (int q = 0; q < 4; ++q)
      dst[q] = make_uint4(buf[q * 4], buf[q * 4 + 1], buf[q * 4 + 2], buf[q * 4 + 3]);
  }
}

// part[chunk][r] = sum over 256 tile rows t in chunk of 2^( avv[t] + stat_r . tile_t )
// GRID: x = chunk (fast-varying), y = stationary group. Concurrent blocks share
// the y-group's stationary panel (L2-hit after first fetch); the 32 tiles
// (512 KB total) are read once per XCD and stay L2-resident for later rows.
__global__ __launch_bounds__(256, 4) void k_pass(
    const unsigned int* __restrict__ tilev,
    const unsigned int* __restrict__ statv,
    const float* __restrict__ avv,
    float* __restrict__ part) {
  __shared__ __align__(16) float tl[256 * 20];  // 64B data + 16B pad per row
  __shared__ __align__(16) float av_lds[256];
  const int t = threadIdx.x;
  const int chunk = blockIdx.x;   // fast dim
  const int sg    = blockIdx.y;   // stationary group
  {
    const float4* src = (const float4*)(tilev + (size_t)chunk * 256 * 16);
#pragma unroll
    for (int q = 0; q < 4; ++q) {
      int f = t + 256 * q;
      int row = f >> 2, prt = f & 3;
      *(float4*)(tl + row * 20 + prt * 4) = src[f];
    }
    av_lds[t] = avv[chunk * 256 + t];
  }
  __syncthreads();

  const int wave = t >> 6;
  const int l = t & 63;
  const int lr = l & 15;   // A-row / D-col / B-col selector
  const int g = l >> 4;    // k-group
  const int r0 = (sg * 4 + wave) * 64;

  bf16x8 b1[4], b2[4];
#pragma unroll
  for (int s = 0; s < 4; ++s) {
    const unsigned int* rowp = statv + (size_t)(r0 + s * 16 + lr) * 16;
    b1[s] = *(const bf16x8*)(rowp + (g & 1) * 4);      // [bh | bh]
    b2[s] = *(const bf16x8*)(rowp + 8 + (g & 1) * 4);  // [bl | bl]
  }

  float acc[4] = {0.f, 0.f, 0.f, 0.f};
#pragma unroll
  for (int tile = 0; tile < 16; ++tile) {
    const bf16x8 af = *(const bf16x8*)(tl + (tile * 16 + lr) * 20 + g * 4);
    const f32x4 avf = *(const f32x4*)(av_lds + tile * 16 + g * 4);
#pragma unroll
    for (int s = 0; s < 4; ++s) {
      f32x4 d = __builtin_amdgcn_mfma_f32_16x16x32_bf16(af, b1[s], avf, 0, 0, 0);
      d = __builtin_amdgcn_mfma_f32_16x16x32_bf16(af, b2[s], d, 0, 0, 0);
      acc[s] += (fast_exp2(d[0]) + fast_exp2(d[1])) + (fast_exp2(d[2]) + fast_exp2(d[3]));
    }
  }
#pragma unroll
  for (int s = 0; s < 4; ++s) {
    float v = acc[s];
    v += __shfl_xor(v, 16);
    v += __shfl_xor(v, 32);
    if (l < 16) part[(size_t)chunk * 8192 + r0 + s * 16 + l] = v;
  }
}

__global__ __launch_bounds__(256) void k_red_a2(
    const float* __restrict__ part, const float* __restrict__ w,
    float* __restrict__ av2) {
  int i = blockIdx.x * 256 + threadIdx.x;
  float s = 0.f;
#pragma unroll
  for (int c = 0; c < 32; ++c) s += part[(size_t)c * 8192 + i];
  av2[i] = LOG2E * w[i] - fast_log2(s);
}

__global__ __launch_bounds__(256) void k_out(
    const float* __restrict__ part, const float* __restrict__ av1,
    float* __restrict__ out) {
  int j = blockIdx.x * 256 + threadIdx.x;
  float s = 0.f;
#pragma unroll
  for (int c = 0; c < 32; ++c) s += part[(size_t)c * 8192 + j];
  out[j] = LN2 * (av1[j] + fast_log2(s));
}

extern "C" void kernel_launch(void* const* d_in, const int* in_sizes, int n_in,
                              void* d_out, int out_size, void* d_ws, size_t ws_size,
                              hipStream_t stream) {
  const float* particles = (const float*)d_in[0];
  const float* lw        = (const float*)d_in[1];
  const float* sp        = (const float*)d_in[2];
  const float* w         = (const float*)d_in[3];
  const float* A         = (const float*)d_in[4];
  const float* B         = (const float*)d_in[5];

  float* ws = (float*)d_ws;
  unsigned int* muP = (unsigned int*)(ws + WS_MUP);
  unsigned int* spT = (unsigned int*)(ws + WS_SPT);
  float* av1  = ws + WS_AV1;
  float* av2  = ws + WS_AV2;
  float* part = ws + WS_PART;
  float* out  = (float*)d_out;

  k_prep<<<dim3(32), dim3(256), 0, stream>>>(particles, lw, sp, A, B, muP, spT, av1);
  // pass 1: tile = mu (j), stationary = sp' (i)  -> S1 per i
  k_pass<<<dim3(32, 32), dim3(256), 0, stream>>>(muP, spT, av1, part);
  k_red_a2<<<dim3(32), dim3(256), 0, stream>>>(part, w, av2);
  // pass 2: tile = sp' (i), stationary = mu (j)  -> S2 per j
  k_pass<<<dim3(32, 32), dim3(256), 0, stream>>>(spT, muP, av2, part);
  k_out<<<dim3(32), dim3(256), 0, stream>>>(part, av1, out);
}

// Round 5
// 63.728 us; speedup vs baseline: 2.4239x; 1.3762x over previous
//
#include <hip/hip_runtime.h>

#define LOG2E 1.44269504088896340736f
#define LN2   0.69314718055994530942f

typedef __attribute__((ext_vector_type(8))) short bf16x8;
typedef __attribute__((ext_vector_type(4))) float f32x4;

// ws float offsets
#define WS_MUP  0        // 8192 x 16 u32 : packed [mu_hi(16)|mu_lo(16)] bf16
#define WS_SPT  131072   // 8192 x 16 u32 : packed [sp'_hi|sp'_lo], sp' = log2e*sp
#define WS_AV1  262144   // 8192 f32
#define WS_AV2  270336   // 8192 f32
#define WS_P1   278528   // 64 x 8192 f32 partials, pass 1
#define WS_P2   802816   // 64 x 8192 f32 partials, pass 2
// end 1327104 floats = 5.3 MB

__device__ __forceinline__ unsigned short bf16_rne(float x) {
  unsigned int u = __float_as_uint(x);
  u = u + 0x7FFFu + ((u >> 16) & 1u);
  return (unsigned short)(u >> 16);
}
__device__ __forceinline__ float bf16f(unsigned short h) {
  return __uint_as_float(((unsigned int)h) << 16);
}
__device__ __forceinline__ float fast_exp2(float x) {
#if __has_builtin(__builtin_amdgcn_exp2f)
  return __builtin_amdgcn_exp2f(x);
#else
  return exp2f(x);
#endif
}
__device__ __forceinline__ float fast_log2(float x) {
#if __has_builtin(__builtin_amdgcn_logf)
  return __builtin_amdgcn_logf(x);
#else
  return log2f(x);
#endif
}

__device__ __forceinline__ void pack_row(const float* v, unsigned int* buf) {
#pragma unroll
  for (int k = 0; k < 16; k += 2) {
    unsigned short h0 = bf16_rne(v[k]);
    unsigned short h1 = bf16_rne(v[k + 1]);
    float l0 = v[k] - bf16f(h0);
    float l1 = v[k + 1] - bf16f(h1);
    buf[k >> 1] = (unsigned int)h0 | ((unsigned int)h1 << 16);
    buf[8 + (k >> 1)] = (unsigned int)bf16_rne(l0) | ((unsigned int)bf16_rne(l1) << 16);
  }
}

__global__ __launch_bounds__(256) void k_prep(
    const float* __restrict__ particles, const float* __restrict__ lw,
    const float* __restrict__ sp,
    const float* __restrict__ A, const float* __restrict__ B,
    unsigned int* __restrict__ muP, unsigned int* __restrict__ spT,
    float* __restrict__ av1) {
  int j = blockIdx.x * 256 + threadIdx.x;
  float x[24];
  {
    const float4* p4 = (const float4*)(particles + (size_t)j * 24);
#pragma unroll
    for (int q = 0; q < 6; ++q) {
      float4 v = p4[q];
      x[q * 4 + 0] = v.x; x[q * 4 + 1] = v.y; x[q * 4 + 2] = v.z; x[q * 4 + 3] = v.w;
    }
  }
  float mrow[16];
  float m2 = 0.f;
#pragma unroll
  for (int k = 0; k < 16; ++k) {
    float s = 0.f;
#pragma unroll
    for (int l = 0; l < 16; ++l) s += x[l] * A[k * 16 + l];
#pragma unroll
    for (int l = 0; l < 8; ++l) s += x[16 + l] * B[k * 8 + l];
    mrow[k] = s;
    m2 += s * s;
  }
  av1[j] = LOG2E * (lw[j] - 0.5f * m2);

  unsigned int buf[16];
  pack_row(mrow, buf);
  {
    uint4* dst = (uint4*)(muP + (size_t)j * 16);
#pragma unroll
    for (int q = 0; q < 4; ++q)
      dst[q] = make_uint4(buf[q * 4], buf[q * 4 + 1], buf[q * 4 + 2], buf[q * 4 + 3]);
  }
  float srow[16];
  {
    const float4* s4 = (const float4*)(sp + (size_t)j * 16);
#pragma unroll
    for (int q = 0; q < 4; ++q) {
      float4 v = s4[q];
      srow[q * 4 + 0] = LOG2E * v.x; srow[q * 4 + 1] = LOG2E * v.y;
      srow[q * 4 + 2] = LOG2E * v.z; srow[q * 4 + 3] = LOG2E * v.w;
    }
  }
  pack_row(srow, buf);
  {
    uint4* dst = (uint4*)(spT + (size_t)j * 16);
#pragma unroll
    for (int q = 0; q < 4; ++q)
      dst[q] = make_uint4(buf[q * 4], buf[q * 4 + 1], buf[q * 4 + 2], buf[q * 4 + 3]);
  }
}

// part[chunk][r] = sum over 128 tile rows t in chunk of 2^( av[t] + stat_r . tile_t )
// Grid (64 chunks, 64 stationary groups); block = 4 waves; each wave owns 32
// stationary rows (2 strips of 16, frags in regs); tile chunk = 128 rows in LDS.
// 8 blocks/CU (full 32-wave occupancy): LDS 10.75 KB, VGPR <= 64.
__global__ __launch_bounds__(256, 8) void k_pass(
    const unsigned int* __restrict__ tilev,
    const unsigned int* __restrict__ statv,
    const float* __restrict__ avv,
    float* __restrict__ part) {
  __shared__ __align__(16) float tl[128 * 20];  // 64B data + 16B pad per row
  __shared__ __align__(16) float av_lds[128];
  const int t = threadIdx.x;
  const int chunk = blockIdx.x;  // 0..63
  const int sg    = blockIdx.y;  // 0..63
  {
    const float4* src = (const float4*)(tilev + (size_t)chunk * 128 * 16);
#pragma unroll
    for (int q = 0; q < 2; ++q) {
      int f = t + 256 * q;
      int row = f >> 2, prt = f & 3;
      *(float4*)(tl + row * 20 + prt * 4) = src[f];
    }
    if (t < 128) av_lds[t] = avv[chunk * 128 + t];
  }
  __syncthreads();

  const int wave = t >> 6;
  const int l = t & 63;
  const int lr = l & 15;
  const int g = l >> 4;
  const int r0 = (sg * 4 + wave) * 32;

  bf16x8 b1[2], b2[2];
#pragma unroll
  for (int s = 0; s < 2; ++s) {
    const unsigned int* rowp = statv + (size_t)(r0 + s * 16 + lr) * 16;
    b1[s] = *(const bf16x8*)(rowp + (g & 1) * 4);
    b2[s] = *(const bf16x8*)(rowp + 8 + (g & 1) * 4);
  }

  float acc[2] = {0.f, 0.f};
#pragma unroll
  for (int tile = 0; tile < 8; ++tile) {
    const bf16x8 af = *(const bf16x8*)(tl + (tile * 16 + lr) * 20 + g * 4);
    const f32x4 avf = *(const f32x4*)(av_lds + tile * 16 + g * 4);
#pragma unroll
    for (int s = 0; s < 2; ++s) {
      f32x4 d = __builtin_amdgcn_mfma_f32_16x16x32_bf16(af, b1[s], avf, 0, 0, 0);
      d = __builtin_amdgcn_mfma_f32_16x16x32_bf16(af, b2[s], d, 0, 0, 0);
      acc[s] += (fast_exp2(d[0]) + fast_exp2(d[1])) + (fast_exp2(d[2]) + fast_exp2(d[3]));
    }
  }
#pragma unroll
  for (int s = 0; s < 2; ++s) {
    float v = acc[s];
    v += __shfl_xor(v, 16);
    v += __shfl_xor(v, 32);
    if (l < 16) part[(size_t)chunk * 8192 + r0 + s * 16 + l] = v;
  }
}

__global__ __launch_bounds__(256) void k_red_a2(
    const float* __restrict__ part, const float* __restrict__ w,
    float* __restrict__ av2) {
  int i = blockIdx.x * 256 + threadIdx.x;
  float s = 0.f;
#pragma unroll
  for (int c = 0; c < 64; ++c) s += part[(size_t)c * 8192 + i];
  av2[i] = LOG2E * w[i] - fast_log2(s);
}

__global__ __launch_bounds__(256) void k_out(
    const float* __restrict__ part, const float* __restrict__ av1,
    float* __restrict__ out) {
  int j = blockIdx.x * 256 + threadIdx.x;
  float s = 0.f;
#pragma unroll
  for (int c = 0; c < 64; ++c) s += part[(size_t)c * 8192 + j];
  out[j] = LN2 * (av1[j] + fast_log2(s));
}

extern "C" void kernel_launch(void* const* d_in, const int* in_sizes, int n_in,
                              void* d_out, int out_size, void* d_ws, size_t ws_size,
                              hipStream_t stream) {
  const float* particles = (const float*)d_in[0];
  const float* lw        = (const float*)d_in[1];
  const float* sp        = (const float*)d_in[2];
  const float* w         = (const float*)d_in[3];
  const float* A         = (const float*)d_in[4];
  const float* B         = (const float*)d_in[5];

  float* ws = (float*)d_ws;
  unsigned int* muP = (unsigned int*)(ws + WS_MUP);
  unsigned int* spT = (unsigned int*)(ws + WS_SPT);
  float* av1  = ws + WS_AV1;
  float* av2  = ws + WS_AV2;
  float* p1   = ws + WS_P1;
  float* p2   = ws + WS_P2;
  float* out  = (float*)d_out;

  k_prep<<<dim3(32), dim3(256), 0, stream>>>(particles, lw, sp, A, B, muP, spT, av1);
  // pass 1: tile = mu chunks (j), stationary = sp' (i) -> partials of S1 per i
  k_pass<<<dim3(64, 64), dim3(256), 0, stream>>>(muP, spT, av1, p1);
  k_red_a2<<<dim3(32), dim3(256), 0, stream>>>(p1, w, av2);
  // pass 2: tile = sp' chunks (i), stationary = mu (j) -> partials of S2 per j
  k_pass<<<dim3(64, 64), dim3(256), 0, stream>>>(spT, muP, av2, p2);
  k_out<<<dim3(32), dim3(256), 0, stream>>>(p2, av1, out);
}

// Round 6
// 56.017 us; speedup vs baseline: 2.7575x; 1.1376x over previous
//
#include <hip/hip_runtime.h>

#define LOG2E 1.44269504088896340736f
#define LN2   0.69314718055994530942f

typedef __attribute__((ext_vector_type(8))) short bf16x8;
typedef __attribute__((ext_vector_type(4))) float f32x4;
typedef __attribute__((ext_vector_type(16))) float f32x16;

// ws float offsets
#define WS_MUP  0        // 8192 x 16 u32 : packed [mu_hi(16)|mu_lo(16)] bf16
#define WS_SPT  131072   // 8192 x 16 u32 : packed [sp'_hi|sp'_lo], sp' = log2e*sp
#define WS_AV1  262144   // 8192 f32
#define WS_P1   270336   // 64 x 8192 f32 partials, pass 1
#define WS_P2   794624   // 64 x 8192 f32 partials, pass 2
// end 1318912 floats = 5.3 MB

__device__ __forceinline__ unsigned short bf16_rne(float x) {
  unsigned int u = __float_as_uint(x);
  u = u + 0x7FFFu + ((u >> 16) & 1u);
  return (unsigned short)(u >> 16);
}
__device__ __forceinline__ float bf16f(unsigned short h) {
  return __uint_as_float(((unsigned int)h) << 16);
}
__device__ __forceinline__ float fast_exp2(float x) {
#if __has_builtin(__builtin_amdgcn_exp2f)
  return __builtin_amdgcn_exp2f(x);
#else
  return exp2f(x);
#endif
}
__device__ __forceinline__ float fast_log2(float x) {
#if __has_builtin(__builtin_amdgcn_logf)
  return __builtin_amdgcn_logf(x);
#else
  return log2f(x);
#endif
}

__device__ __forceinline__ void pack_row(const float* v, unsigned int* buf) {
#pragma unroll
  for (int k = 0; k < 16; k += 2) {
    unsigned short h0 = bf16_rne(v[k]);
    unsigned short h1 = bf16_rne(v[k + 1]);
    float l0 = v[k] - bf16f(h0);
    float l1 = v[k + 1] - bf16f(h1);
    buf[k >> 1] = (unsigned int)h0 | ((unsigned int)h1 << 16);
    buf[8 + (k >> 1)] = (unsigned int)bf16_rne(l0) | ((unsigned int)bf16_rne(l1) << 16);
  }
}

__global__ __launch_bounds__(256) void k_prep(
    const float* __restrict__ particles, const float* __restrict__ lw,
    const float* __restrict__ sp,
    const float* __restrict__ A, const float* __restrict__ B,
    unsigned int* __restrict__ muP, unsigned int* __restrict__ spT,
    float* __restrict__ av1) {
  int j = blockIdx.x * 256 + threadIdx.x;
  float x[24];
  {
    const float4* p4 = (const float4*)(particles + (size_t)j * 24);
#pragma unroll
    for (int q = 0; q < 6; ++q) {
      float4 v = p4[q];
      x[q * 4 + 0] = v.x; x[q * 4 + 1] = v.y; x[q * 4 + 2] = v.z; x[q * 4 + 3] = v.w;
    }
  }
  float mrow[16];
  float m2 = 0.f;
#pragma unroll
  for (int k = 0; k < 16; ++k) {
    float s = 0.f;
#pragma unroll
    for (int l = 0; l < 16; ++l) s += x[l] * A[k * 16 + l];
#pragma unroll
    for (int l = 0; l < 8; ++l) s += x[16 + l] * B[k * 8 + l];
    mrow[k] = s;
    m2 += s * s;
  }
  av1[j] = LOG2E * (lw[j] - 0.5f * m2);

  unsigned int buf[16];
  pack_row(mrow, buf);
  {
    uint4* dst = (uint4*)(muP + (size_t)j * 16);
#pragma unroll
    for (int q = 0; q < 4; ++q)
      dst[q] = make_uint4(buf[q * 4], buf[q * 4 + 1], buf[q * 4 + 2], buf[q * 4 + 3]);
  }
  float srow[16];
  {
    const float4* s4 = (const float4*)(sp + (size_t)j * 16);
#pragma unroll
    for (int q = 0; q < 4; ++q) {
      float4 v = s4[q];
      srow[q * 4 + 0] = LOG2E * v.x; srow[q * 4 + 1] = LOG2E * v.y;
      srow[q * 4 + 2] = LOG2E * v.z; srow[q * 4 + 3] = LOG2E * v.w;
    }
  }
  pack_row(srow, buf);
  {
    uint4* dst = (uint4*)(spT + (size_t)j * 16);
#pragma unroll
    for (int q = 0; q < 4; ++q)
      dst[q] = make_uint4(buf[q * 4], buf[q * 4 + 1], buf[q * 4 + 2], buf[q * 4 + 3]);
  }
}

// part[chunk][r] = sum over 128 tile rows t of chunk of 2^( av[t] + stat_r . tile_t )
// 32x32x16 MFMA; no LDS tile (tile rows L1-resident, b-frags L2-resident).
// pass1 (psrc==null): av = avv (=av1).  pass2: av[t] = LOG2E*avv[t] - log2(sum_c psrc[c][t]).
__global__ __launch_bounds__(256, 8) void k_pass(
    const unsigned int* __restrict__ tilev,
    const unsigned int* __restrict__ statv,
    const float* __restrict__ avv,
    const float* __restrict__ psrc,
    float* __restrict__ part) {
  __shared__ __align__(16) float av_l[128];
  __shared__ float sums[256];
  const int t = threadIdx.x;
  const int chunk = blockIdx.x;  // 0..63, fast
  const int sg    = blockIdx.y;  // 0..63

  if (psrc == nullptr) {
    if (t < 128) av_l[t] = avv[chunk * 128 + t];
  } else {
    const int row = t & 127, half = t >> 7;
    float s = 0.f;
    const float* p = psrc + (size_t)(half * 32) * 8192 + chunk * 128 + row;
#pragma unroll 8
    for (int c = 0; c < 32; ++c) s += p[(size_t)c * 8192];
    sums[t] = s;
    __syncthreads();
    if (t < 128) {
      float sv = sums[t] + sums[t + 128];
      av_l[t] = LOG2E * avv[chunk * 128 + t] - fast_log2(sv);
    }
  }
  __syncthreads();

  const int l = t & 63;
  const int wave = t >> 6;
  const int lr = l & 31;   // A-row / B-col / D-col selector
  const int hi = l >> 5;   // k-half selector
  const int r0 = sg * 128 + wave * 32;

  // stationary B fragments (row r0+lr, k-half hi): hi part and lo part
  const unsigned int* brow = statv + (size_t)(r0 + lr) * 16 + hi * 4;
  const bf16x8 b_hi = *(const bf16x8*)brow;
  const bf16x8 b_lo = *(const bf16x8*)(brow + 8);

  float acc = 0.f;
#pragma unroll
  for (int tile = 0; tile < 4; ++tile) {
    const unsigned int* arow =
        tilev + (size_t)(chunk * 128 + tile * 32 + lr) * 16 + hi * 4;
    const bf16x8 a_hi = *(const bf16x8*)arow;
    const bf16x8 a_lo = *(const bf16x8*)(arow + 8);

    // C init = av[tile row]; C row = (reg&3) + 8*(reg>>2) + 4*hi
    f32x16 d;
#pragma unroll
    for (int q = 0; q < 4; ++q) {
      const f32x4 v = *(const f32x4*)(av_l + tile * 32 + 8 * q + 4 * hi);
      d[4 * q + 0] = v[0]; d[4 * q + 1] = v[1];
      d[4 * q + 2] = v[2]; d[4 * q + 3] = v[3];
    }
    d = __builtin_amdgcn_mfma_f32_32x32x16_bf16(a_hi, b_hi, d, 0, 0, 0);
    d = __builtin_amdgcn_mfma_f32_32x32x16_bf16(a_lo, b_hi, d, 0, 0, 0);
    d = __builtin_amdgcn_mfma_f32_32x32x16_bf16(a_hi, b_lo, d, 0, 0, 0);
    d = __builtin_amdgcn_mfma_f32_32x32x16_bf16(a_lo, b_lo, d, 0, 0, 0);

    float e0 = fast_exp2(d[0])  + fast_exp2(d[1]);
    float e1 = fast_exp2(d[2])  + fast_exp2(d[3]);
    float e2 = fast_exp2(d[4])  + fast_exp2(d[5]);
    float e3 = fast_exp2(d[6])  + fast_exp2(d[7]);
    float e4 = fast_exp2(d[8])  + fast_exp2(d[9]);
    float e5 = fast_exp2(d[10]) + fast_exp2(d[11]);
    float e6 = fast_exp2(d[12]) + fast_exp2(d[13]);
    float e7 = fast_exp2(d[14]) + fast_exp2(d[15]);
    acc += ((e0 + e1) + (e2 + e3)) + ((e4 + e5) + (e6 + e7));
  }
  acc += __shfl_xor(acc, 32);
  if (l < 32) part[(size_t)chunk * 8192 + r0 + lr] = acc;
}

__global__ __launch_bounds__(256) void k_out(
    const float* __restrict__ part, const float* __restrict__ av1,
    float* __restrict__ out) {
  int j = blockIdx.x * 256 + threadIdx.x;
  float s = 0.f;
#pragma unroll
  for (int c = 0; c < 64; ++c) s += part[(size_t)c * 8192 + j];
  out[j] = LN2 * (av1[j] + fast_log2(s));
}

extern "C" void kernel_launch(void* const* d_in, const int* in_sizes, int n_in,
                              void* d_out, int out_size, void* d_ws, size_t ws_size,
                              hipStream_t stream) {
  const float* particles = (const float*)d_in[0];
  const float* lw        = (const float*)d_in[1];
  const float* sp        = (const float*)d_in[2];
  const float* w         = (const float*)d_in[3];
  const float* A         = (const float*)d_in[4];
  const float* B         = (const float*)d_in[5];

  float* ws = (float*)d_ws;
  unsigned int* muP = (unsigned int*)(ws + WS_MUP);
  unsigned int* spT = (unsigned int*)(ws + WS_SPT);
  float* av1  = ws + WS_AV1;
  float* p1   = ws + WS_P1;
  float* p2   = ws + WS_P2;
  float* out  = (float*)d_out;

  k_prep<<<dim3(32), dim3(256), 0, stream>>>(particles, lw, sp, A, B, muP, spT, av1);
  // pass 1: tile = mu chunks (j, av1), stationary = sp' (i) -> S1 partials per i
  k_pass<<<dim3(64, 64), dim3(256), 0, stream>>>(muP, spT, av1, nullptr, p1);
  // pass 2: tile = sp' chunks (i, av2 computed in prologue), stationary = mu (j)
  k_pass<<<dim3(64, 64), dim3(256), 0, stream>>>(spT, muP, w, p1, p2);
  k_out<<<dim3(32), dim3(256), 0, stream>>>(p2, av1, out);
}

// Round 7
// 49.819 us; speedup vs baseline: 3.1006x; 1.1244x over previous
//
#include <hip/hip_runtime.h>

#define LOG2E 1.44269504088896340736f
#define LN2   0.69314718055994530942f

typedef __attribute__((ext_vector_type(8))) short bf16x8;
typedef __attribute__((ext_vector_type(4))) float f32x4;
typedef __attribute__((ext_vector_type(16))) float f32x16;

// ws float offsets
#define WS_MUP  0        // 8192 x 16 u32 : packed [mu_hi(16)|mu_lo(16)] bf16
#define WS_SPT  131072   // 8192 x 16 u32 : packed [sp'_hi|sp'_lo], sp' = log2e*sp
#define WS_AV1  262144   // 8192 f32
#define WS_P1   270336   // 64 x 8192 f32 partials, pass 1
#define WS_P2   794624   // 64 x 8192 f32 partials, pass 2

__device__ __forceinline__ unsigned short bf16_rne(float x) {
  unsigned int u = __float_as_uint(x);
  u = u + 0x7FFFu + ((u >> 16) & 1u);
  return (unsigned short)(u >> 16);
}
__device__ __forceinline__ float bf16f(unsigned short h) {
  return __uint_as_float(((unsigned int)h) << 16);
}
__device__ __forceinline__ float fast_exp2(float x) {
#if __has_builtin(__builtin_amdgcn_exp2f)
  return __builtin_amdgcn_exp2f(x);
#else
  return exp2f(x);
#endif
}
__device__ __forceinline__ float fast_log2(float x) {
#if __has_builtin(__builtin_amdgcn_logf)
  return __builtin_amdgcn_logf(x);
#else
  return log2f(x);
#endif
}

__device__ __forceinline__ void pack_row(const float* v, unsigned int* buf) {
#pragma unroll
  for (int k = 0; k < 16; k += 2) {
    unsigned short h0 = bf16_rne(v[k]);
    unsigned short h1 = bf16_rne(v[k + 1]);
    float l0 = v[k] - bf16f(h0);
    float l1 = v[k + 1] - bf16f(h1);
    buf[k >> 1] = (unsigned int)h0 | ((unsigned int)h1 << 16);
    buf[8 + (k >> 1)] = (unsigned int)bf16_rne(l0) | ((unsigned int)bf16_rne(l1) << 16);
  }
}

__global__ __launch_bounds__(256) void k_prep(
    const float* __restrict__ particles, const float* __restrict__ lw,
    const float* __restrict__ sp,
    const float* __restrict__ A, const float* __restrict__ B,
    unsigned int* __restrict__ muP, unsigned int* __restrict__ spT,
    float* __restrict__ av1) {
  int j = blockIdx.x * 256 + threadIdx.x;
  float x[24];
  {
    const float4* p4 = (const float4*)(particles + (size_t)j * 24);
#pragma unroll
    for (int q = 0; q < 6; ++q) {
      float4 v = p4[q];
      x[q * 4 + 0] = v.x; x[q * 4 + 1] = v.y; x[q * 4 + 2] = v.z; x[q * 4 + 3] = v.w;
    }
  }
  float mrow[16];
  float m2 = 0.f;
#pragma unroll
  for (int k = 0; k < 16; ++k) {
    float s = 0.f;
#pragma unroll
    for (int l = 0; l < 16; ++l) s += x[l] * A[k * 16 + l];
#pragma unroll
    for (int l = 0; l < 8; ++l) s += x[16 + l] * B[k * 8 + l];
    mrow[k] = s;
    m2 += s * s;
  }
  av1[j] = LOG2E * (lw[j] - 0.5f * m2);

  unsigned int buf[16];
  pack_row(mrow, buf);
  {
    uint4* dst = (uint4*)(muP + (size_t)j * 16);
#pragma unroll
    for (int q = 0; q < 4; ++q)
      dst[q] = make_uint4(buf[q * 4], buf[q * 4 + 1], buf[q * 4 + 2], buf[q * 4 + 3]);
  }
  float srow[16];
  {
    const float4* s4 = (const float4*)(sp + (size_t)j * 16);
#pragma unroll
    for (int q = 0; q < 4; ++q) {
      float4 v = s4[q];
      srow[q * 4 + 0] = LOG2E * v.x; srow[q * 4 + 1] = LOG2E * v.y;
      srow[q * 4 + 2] = LOG2E * v.z; srow[q * 4 + 3] = LOG2E * v.w;
    }
  }
  pack_row(srow, buf);
  {
    uint4* dst = (uint4*)(spT + (size_t)j * 16);
#pragma unroll
    for (int q = 0; q < 4; ++q)
      dst[q] = make_uint4(buf[q * 4], buf[q * 4 + 1], buf[q * 4 + 2], buf[q * 4 + 3]);
  }
}

// part[chunk][r] = sum over 128 tile rows t of chunk of 2^( av[t] + stat_r . tile_t )
// 32x32x16 MFMA. Tile staged in LDS, row stride 20 words (80 B): read slot
// (5r+h) mod 8 covers all residues per 16-lane quarter -> conflict-free b128.
// 3-MFMA hi/lo split (lo*lo dropped, ~5e-4 exponent error).
__global__ __launch_bounds__(256, 8) void k_pass(
    const unsigned int* __restrict__ tilev,
    const unsigned int* __restrict__ statv,
    const float* __restrict__ avv,
    const float* __restrict__ psrc,
    float* __restrict__ part) {
  __shared__ __align__(16) unsigned int tl[128 * 20];
  __shared__ __align__(16) float av_l[128];
  __shared__ float sums[256];
  const int t = threadIdx.x;
  const int chunk = blockIdx.x;  // 0..63, fast
  const int sg    = blockIdx.y;  // 0..63

  // stage tile: 128 rows x 16 u32 -> LDS stride 20 (coalesced uint4 src)
  {
    const uint4* src = (const uint4*)(tilev + (size_t)chunk * 2048);
#pragma unroll
    for (int q = 0; q < 2; ++q) {
      int f = t + 256 * q;
      int row = f >> 2, s = f & 3;
      *(uint4*)(tl + row * 20 + s * 4) = src[f];
    }
  }

  if (psrc == nullptr) {
    if (t < 128) av_l[t] = avv[chunk * 128 + t];
  } else {
    const int row = t & 127, half = t >> 7;
    float s = 0.f;
    const float* p = psrc + (size_t)(half * 32) * 8192 + chunk * 128 + row;
#pragma unroll 8
    for (int c = 0; c < 32; ++c) s += p[(size_t)c * 8192];
    sums[t] = s;
    __syncthreads();
    if (t < 128) {
      float sv = sums[t] + sums[t + 128];
      av_l[t] = LOG2E * avv[chunk * 128 + t] - fast_log2(sv);
    }
  }
  __syncthreads();

  const int l = t & 63;
  const int wave = t >> 6;
  const int lr = l & 31;   // A-row / B-col / D-col selector
  const int hi = l >> 5;   // k-half selector
  const int r0 = sg * 128 + wave * 32;

  // stationary B fragments (row r0+lr, k-half hi)
  const unsigned int* brow = statv + (size_t)(r0 + lr) * 16 + hi * 4;
  const bf16x8 b_hi = *(const bf16x8*)brow;
  const bf16x8 b_lo = *(const bf16x8*)(brow + 8);

  float acc = 0.f;
#pragma unroll
  for (int tile = 0; tile < 4; ++tile) {
    const unsigned int* arow = tl + (tile * 32 + lr) * 20 + hi * 4;
    const bf16x8 a_hi = *(const bf16x8*)arow;
    const bf16x8 a_lo = *(const bf16x8*)(arow + 8);

    // C init = av[tile row]; C row = (reg&3) + 8*(reg>>2) + 4*hi
    f32x16 d;
#pragma unroll
    for (int q = 0; q < 4; ++q) {
      const f32x4 v = *(const f32x4*)(av_l + tile * 32 + 8 * q + 4 * hi);
      d[4 * q + 0] = v[0]; d[4 * q + 1] = v[1];
      d[4 * q + 2] = v[2]; d[4 * q + 3] = v[3];
    }
    d = __builtin_amdgcn_mfma_f32_32x32x16_bf16(a_hi, b_hi, d, 0, 0, 0);
    d = __builtin_amdgcn_mfma_f32_32x32x16_bf16(a_lo, b_hi, d, 0, 0, 0);
    d = __builtin_amdgcn_mfma_f32_32x32x16_bf16(a_hi, b_lo, d, 0, 0, 0);

    float e0 = fast_exp2(d[0])  + fast_exp2(d[1]);
    float e1 = fast_exp2(d[2])  + fast_exp2(d[3]);
    float e2 = fast_exp2(d[4])  + fast_exp2(d[5]);
    float e3 = fast_exp2(d[6])  + fast_exp2(d[7]);
    float e4 = fast_exp2(d[8])  + fast_exp2(d[9]);
    float e5 = fast_exp2(d[10]) + fast_exp2(d[11]);
    float e6 = fast_exp2(d[12]) + fast_exp2(d[13]);
    float e7 = fast_exp2(d[14]) + fast_exp2(d[15]);
    acc += ((e0 + e1) + (e2 + e3)) + ((e4 + e5) + (e6 + e7));
  }
  acc += __shfl_xor(acc, 32);
  if (l < 32) part[(size_t)chunk * 8192 + r0 + lr] = acc;
}

__global__ __launch_bounds__(256) void k_out(
    const float* __restrict__ part, const float* __restrict__ av1,
    float* __restrict__ out) {
  int j = blockIdx.x * 256 + threadIdx.x;
  float s = 0.f;
#pragma unroll
  for (int c = 0; c < 64; ++c) s += part[(size_t)c * 8192 + j];
  out[j] = LN2 * (av1[j] + fast_log2(s));
}

extern "C" void kernel_launch(void* const* d_in, const int* in_sizes, int n_in,
                              void* d_out, int out_size, void* d_ws, size_t ws_size,
                              hipStream_t stream) {
  const float* particles = (const float*)d_in[0];
  const float* lw        = (const float*)d_in[1];
  const float* sp        = (const float*)d_in[2];
  const float* w         = (const float*)d_in[3];
  const float* A         = (const float*)d_in[4];
  const float* B         = (const float*)d_in[5];

  float* ws = (float*)d_ws;
  unsigned int* muP = (unsigned int*)(ws + WS_MUP);
  unsigned int* spT = (unsigned int*)(ws + WS_SPT);
  float* av1  = ws + WS_AV1;
  float* p1   = ws + WS_P1;
  float* p2   = ws + WS_P2;
  float* out  = (float*)d_out;

  k_prep<<<dim3(32), dim3(256), 0, stream>>>(particles, lw, sp, A, B, muP, spT, av1);
  // pass 1: tile = mu chunks (j, av1), stationary = sp' (i) -> S1 partials per i
  k_pass<<<dim3(64, 64), dim3(256), 0, stream>>>(muP, spT, av1, nullptr, p1);
  // pass 2: tile = sp' chunks (i, av2 in prologue), stationary = mu (j)
  k_pass<<<dim3(64, 64), dim3(256), 0, stream>>>(spT, muP, w, p1, p2);
  k_out<<<dim3(32), dim3(256), 0, stream>>>(p2, av1, out);
}